// Round 2
// baseline (154.538 us; speedup 1.0000x reference)
//
#include <hip/hip_runtime.h>
#include <hip/hip_bf16.h>

#define N_POS 9216
#define NCHUNK 9
#define BATCH 8
#define CDIM 64
#define HEADS 4
#define EPS 1e-5f

// ws layout: stats fp32(128) | Pparts fp32 (72 chunks x 16 partials x 4096) |
//            Mp fp32 4x(72*4096) | Wbf16 | ybf bf16
#define NPART 16
#define PPARTS_TOT ((size_t)BATCH * NCHUNK * NPART * 4096)
#define MP_SLICE ((size_t)(BATCH * NCHUNK) * 4096)   // floats per head-partial of M
#define WBF_BYTES ((size_t)384 * 64 * 2)

typedef __attribute__((ext_vector_type(8))) short short8;
typedef __attribute__((ext_vector_type(4))) float f32x4;

static __device__ inline unsigned pk2(float a, float b) {
    __hip_bfloat162 h2(__float2bfloat16(a), __float2bfloat16(b));
    return *reinterpret_cast<unsigned*>(&h2);
}
static __device__ inline float bf2f(short s) {
    union { unsigned u; float f; } c; c.u = ((unsigned)(unsigned short)s) << 16; return c.f;
}
static __device__ inline short8 mk8(unsigned a, unsigned b, unsigned c, unsigned d) {
    union { short8 s; unsigned u[4]; } cv;
    cv.u[0] = a; cv.u[1] = b; cv.u[2] = c; cv.u[3] = d; return cv.s;
}

// Wqkv fp32 [384][64] -> bf16 [384][64]; also zeroes GN stats.
__global__ __launch_bounds__(256) void wprep_kernel(const float* __restrict__ Wqkv,
        __hip_bfloat16* __restrict__ wbf, float* __restrict__ stats) {
    int i = blockIdx.x * 256 + threadIdx.x;   // over 6144 float4
    if (i < 6144) {
        float4 v = ((const float4*)Wqkv)[i];
        uint2 u; u.x = pk2(v.x, v.y); u.y = pk2(v.z, v.w);
        ((uint2*)wbf)[i] = u;
    }
    if (i < 128) stats[i] = 0.f;
}

// qkp v2: grid (144, 8), 64 positions per block, 16 per wave.
// Each wave computes ALL 256 q/k channels for its 16 positions:
//   A-frags loaded DIRECT from global x (no staging, no barrier),
//   B-frags from L2-hot wbf.
// k channel-softmax done fully IN-REGISTER via shfl_xor over the 16 l15 lanes
// (D layout: col=lane&15 = channel, row = quad*4+r = position).
// One LDS transpose write (eq / k-tilde, bf16) -> ONE barrier -> per-head
// P(32x32) MFMA over the block's 64 positions -> plain partial write.
// q normalization deferred (rowsum identity, handled in umat).
__global__ __launch_bounds__(256) void qkp_kernel(const float* __restrict__ x,
        const __hip_bfloat16* __restrict__ wbf, float* __restrict__ Pparts) {
    int bx = blockIdx.x;            // 144 = 9 ck x 16 pt
    int b  = blockIdx.y;
    int ck = bx >> 4, pt = bx & 15;
    __shared__ __align__(16) __hip_bfloat16 skT[256][72];   // [ch][pos], 36.9 KB
    int t = threadIdx.x, w = t >> 6, l = t & 63;
    int l15 = l & 15, quad = l >> 4;
    int p0 = bx * 64 + w * 16;      // global position base for this wave

    // ---- A-frags direct from x: lane holds pos p0+l15, ch = ks*32+quad*8+j
    short8 afr[2];
    {
        const float* xb = x + (size_t)b * CDIM * N_POS + p0 + l15;
        #pragma unroll
        for (int ks = 0; ks < 2; ++ks) {
            float v[8];
            #pragma unroll
            for (int j = 0; j < 8; ++j)
                v[j] = xb[(size_t)(ks * 32 + quad * 8 + j) * N_POS];
            afr[ks] = mk8(pk2(v[0], v[1]), pk2(v[2], v[3]),
                          pk2(v[4], v[5]), pk2(v[6], v[7]));
        }
    }

    // ---- qk MFMA: D[pos 16][ch 256]; nt 0..7 = q channels, 8..15 = k channels
    f32x4 acc[16];
    #pragma unroll
    for (int nt = 0; nt < 16; ++nt) acc[nt] = (f32x4){0.f, 0.f, 0.f, 0.f};
    #pragma unroll
    for (int ks = 0; ks < 2; ++ks) {
        #pragma unroll
        for (int nt = 0; nt < 16; ++nt) {
            short8 bw = *reinterpret_cast<const short8*>(
                wbf + (size_t)(nt * 16 + l15) * 64 + ks * 32 + quad * 8);
            acc[nt] = __builtin_amdgcn_mfma_f32_16x16x32_bf16(afr[ks], bw, acc[nt], 0, 0, 0);
        }
    }

    // ---- q: exp fused into transposed LDS write
    #pragma unroll
    for (int nt = 0; nt < 8; ++nt) {
        uint2 u;
        u.x = pk2(__expf(acc[nt][0]), __expf(acc[nt][1]));
        u.y = pk2(__expf(acc[nt][2]), __expf(acc[nt][3]));
        *reinterpret_cast<uint2*>(&skT[nt * 16 + l15][w * 16 + quad * 4]) = u;
    }
    // ---- k: in-register channel softmax (32 ch = 2 nt x 16 l15 lanes), then write
    #pragma unroll
    for (int h = 0; h < 4; ++h) {
        f32x4 a0 = acc[8 + 2 * h], a1 = acc[9 + 2 * h];
        f32x4 e0, e1;
        #pragma unroll
        for (int r = 0; r < 4; ++r) {
            float m = fmaxf(a0[r], a1[r]);
            m = fmaxf(m, __shfl_xor(m, 1));
            m = fmaxf(m, __shfl_xor(m, 2));
            m = fmaxf(m, __shfl_xor(m, 4));
            m = fmaxf(m, __shfl_xor(m, 8));
            float x0 = __expf(a0[r] - m), x1 = __expf(a1[r] - m);
            float s = x0 + x1;
            s += __shfl_xor(s, 1);
            s += __shfl_xor(s, 2);
            s += __shfl_xor(s, 4);
            s += __shfl_xor(s, 8);
            float is = 1.f / s;
            e0[r] = x0 * is; e1[r] = x1 * is;
        }
        uint2 u;
        u.x = pk2(e0[0], e0[1]); u.y = pk2(e0[2], e0[3]);
        *reinterpret_cast<uint2*>(&skT[128 + h * 32 + l15][w * 16 + quad * 4]) = u;
        u.x = pk2(e1[0], e1[1]); u.y = pk2(e1[2], e1[3]);
        *reinterpret_cast<uint2*>(&skT[128 + h * 32 + 16 + l15][w * 16 + quad * 4]) = u;
    }
    __syncthreads();   // the ONLY barrier

    // ---- P MFMA: wave w = head w; P[d 32][dd 32], K = 64 block positions
    f32x4 pac[2][2];
    pac[0][0] = (f32x4){0,0,0,0}; pac[0][1] = (f32x4){0,0,0,0};
    pac[1][0] = (f32x4){0,0,0,0}; pac[1][1] = (f32x4){0,0,0,0};
    #pragma unroll
    for (int ks = 0; ks < 2; ++ks) {
        int k0 = ks * 32 + quad * 8;
        short8 aq0 = *reinterpret_cast<const short8*>(&skT[w * 32 + l15][k0]);
        short8 aq1 = *reinterpret_cast<const short8*>(&skT[w * 32 + 16 + l15][k0]);
        short8 bk0 = *reinterpret_cast<const short8*>(&skT[128 + w * 32 + l15][k0]);
        short8 bk1 = *reinterpret_cast<const short8*>(&skT[128 + w * 32 + 16 + l15][k0]);
        pac[0][0] = __builtin_amdgcn_mfma_f32_16x16x32_bf16(aq0, bk0, pac[0][0], 0, 0, 0);
        pac[0][1] = __builtin_amdgcn_mfma_f32_16x16x32_bf16(aq0, bk1, pac[0][1], 0, 0, 0);
        pac[1][0] = __builtin_amdgcn_mfma_f32_16x16x32_bf16(aq1, bk0, pac[1][0], 0, 0, 0);
        pac[1][1] = __builtin_amdgcn_mfma_f32_16x16x32_bf16(aq1, bk1, pac[1][1], 0, 0, 0);
    }
    float* Pp = Pparts + (((size_t)(b * NCHUNK + ck) * NPART + pt) * 4 + w) * 1024;
    #pragma unroll
    for (int tA = 0; tA < 2; ++tA)
        #pragma unroll
        for (int tB = 0; tB < 2; ++tB)
            #pragma unroll
            for (int r = 0; r < 4; ++r)
                Pp[(tA * 16 + quad * 4 + r) * 32 + tB * 16 + l15] = pac[tA][tB][r];
}

// Per (ck, b, h): sum 16 partials -> P; iZ = 1/rowsum; U'_h = Wout_h.diag(iZ).P;
// M-partial_h = U'_h . Wv_h (64x64 fp32). y-kernel sums the 4 head-partials.
__global__ __launch_bounds__(256) void umat_kernel(const float* __restrict__ Wout,
        const float* __restrict__ Wqkv, const float* __restrict__ Pparts,
        float* __restrict__ Mp) {
    int ck = blockIdx.x, b = blockIdx.y, h = blockIdx.z;
    int t = threadIdx.x;
    __shared__ float Pl[32][32];
    __shared__ float iZ[32];
    __shared__ float Ul[64][33];    // U'_h, +1 pad
    __shared__ float Wvh[32][68];   // Wv rows of this head, fp32, padded
    {
        const float4* P0 = (const float4*)Pparts
            + ((size_t)(b * NCHUNK + ck) * NPART) * 1024 + h * 256 + t;
        float4 s = (float4){0.f, 0.f, 0.f, 0.f};
        #pragma unroll
        for (int pt = 0; pt < NPART; ++pt) {
            float4 a = P0[pt * 1024];
            s.x += a.x; s.y += a.y; s.z += a.z; s.w += a.w;
        }
        ((float4*)Pl)[t] = s;
    }
    {   // stage Wv_h
        int e = t >> 3, cq = t & 7;
        const float4* wr = (const float4*)(Wqkv + (size_t)(256 + h * 32 + e) * 64 + cq * 8);
        float4 a0 = wr[0], a1 = wr[1];
        *reinterpret_cast<float4*>(&Wvh[e][cq * 8])     = a0;
        *reinterpret_cast<float4*>(&Wvh[e][cq * 8 + 4]) = a1;
    }
    __syncthreads();
    if (t < 32) {
        float s = 0.f;
        #pragma unroll
        for (int c = 0; c < 32; ++c) s += Pl[t][c];
        iZ[t] = 1.f / s;
    }
    __syncthreads();
    int o = t & 63, wv = t >> 6;
    float wz[32];
    {
        const float4* wr = (const float4*)(Wout + (size_t)o * 128 + h * 32);
        #pragma unroll
        for (int j = 0; j < 8; ++j) {
            float4 f = wr[j];
            wz[j*4+0] = f.x * iZ[j*4+0]; wz[j*4+1] = f.y * iZ[j*4+1];
            wz[j*4+2] = f.z * iZ[j*4+2]; wz[j*4+3] = f.w * iZ[j*4+3];
        }
    }
    float ua[8];
    #pragma unroll
    for (int j = 0; j < 8; ++j) ua[j] = 0.f;
    for (int d = 0; d < 32; ++d) {
        float wd = wz[d];
        #pragma unroll
        for (int j = 0; j < 8; ++j) ua[j] += wd * Pl[d][wv * 8 + j];
    }
    #pragma unroll
    for (int j = 0; j < 8; ++j) Ul[o][wv * 8 + j] = ua[j];
    __syncthreads();

    float macc[16];
    #pragma unroll
    for (int j = 0; j < 16; ++j) macc[j] = 0.f;
    for (int e = 0; e < 32; ++e) {
        float u = Ul[o][e];
        const float4* wvp = reinterpret_cast<const float4*>(&Wvh[e][wv * 16]);
        #pragma unroll
        for (int q = 0; q < 4; ++q) {
            float4 f = wvp[q];
            macc[q*4+0] += u * f.x; macc[q*4+1] += u * f.y;
            macc[q*4+2] += u * f.z; macc[q*4+3] += u * f.w;
        }
    }
    float* mp = Mp + (size_t)h * MP_SLICE + ((size_t)(b * NCHUNK + ck)) * 4096
              + (size_t)o * 64 + wv * 16;
    #pragma unroll
    for (int q = 0; q < 4; ++q) {
        float4 f; f.x = macc[q*4+0]; f.y = macc[q*4+1]; f.z = macc[q*4+2]; f.w = macc[q*4+3];
        reinterpret_cast<float4*>(mp)[q] = f;
    }
}

// y v2: LDS-free. Grid (72, 8), 128 positions/block, 32 per wave.
// A-frags: M rows summed over 4 fp32 head-partials (L2), cvt bf16 in-register.
// B-frags: x direct from global. 16 MFMA, fused bias + GN stats.
__global__ __launch_bounds__(256) void y_kernel(const float* __restrict__ x,
        const float* __restrict__ Mp, const float* __restrict__ bout,
        __hip_bfloat16* __restrict__ ybf, float* __restrict__ stats) {
    int bx = blockIdx.x;   // 72 tiles of 128 positions
    int b  = blockIdx.y;
    int ck = bx >> 3;
    int n0 = bx * 128;
    __shared__ float gsum[8], gsq[8];
    int t = threadIdx.x, w = t >> 6, l = t & 63;
    int l15 = l & 15, quad = l >> 4;
    if (t < 8) { gsum[t] = 0.f; gsq[t] = 0.f; }
    __syncthreads();

    // M frags: sum 4 head-partials, pack to bf16
    short8 mf[4][2];
    {
        const float* Mb = Mp + (size_t)(b * NCHUNK + ck) * 4096;
        #pragma unroll
        for (int mt = 0; mt < 4; ++mt)
            #pragma unroll
            for (int ks = 0; ks < 2; ++ks) {
                const float* m0 = Mb + (size_t)(mt * 16 + l15) * 64 + ks * 32 + quad * 8;
                float4 s0 = *reinterpret_cast<const float4*>(m0);
                float4 s1 = *reinterpret_cast<const float4*>(m0 + 4);
                #pragma unroll
                for (int h = 1; h < 4; ++h) {
                    const float* mh = m0 + (size_t)h * MP_SLICE;
                    float4 a0 = *reinterpret_cast<const float4*>(mh);
                    float4 a1 = *reinterpret_cast<const float4*>(mh + 4);
                    s0.x += a0.x; s0.y += a0.y; s0.z += a0.z; s0.w += a0.w;
                    s1.x += a1.x; s1.y += a1.y; s1.z += a1.z; s1.w += a1.w;
                }
                mf[mt][ks] = mk8(pk2(s0.x, s0.y), pk2(s0.z, s0.w),
                                 pk2(s1.x, s1.y), pk2(s1.z, s1.w));
            }
    }
    // x frags: lane holds pos n0+w*32+nt*16+l15, ch = ks*32+quad*8+j
    short8 xf[2][2];
    {
        const float* xb = x + (size_t)b * CDIM * N_POS + n0 + w * 32 + l15;
        #pragma unroll
        for (int nt = 0; nt < 2; ++nt)
            #pragma unroll
            for (int ks = 0; ks < 2; ++ks) {
                float v[8];
                #pragma unroll
                for (int j = 0; j < 8; ++j)
                    v[j] = xb[(size_t)(ks * 32 + quad * 8 + j) * N_POS + nt * 16];
                xf[nt][ks] = mk8(pk2(v[0], v[1]), pk2(v[2], v[3]),
                                 pk2(v[4], v[5]), pk2(v[6], v[7]));
            }
    }
    f32x4 acc[4][2];
    #pragma unroll
    for (int mt = 0; mt < 4; ++mt) { acc[mt][0] = (f32x4){0,0,0,0}; acc[mt][1] = (f32x4){0,0,0,0}; }
    #pragma unroll
    for (int ks = 0; ks < 2; ++ks)
        #pragma unroll
        for (int mt = 0; mt < 4; ++mt) {
            acc[mt][0] = __builtin_amdgcn_mfma_f32_16x16x32_bf16(mf[mt][ks], xf[0][ks], acc[mt][0], 0, 0, 0);
            acc[mt][1] = __builtin_amdgcn_mfma_f32_16x16x32_bf16(mf[mt][ks], xf[1][ks], acc[mt][1], 0, 0, 0);
        }

    float gsl[4], gql[4];
    #pragma unroll
    for (int mt = 0; mt < 4; ++mt) { gsl[mt] = 0.f; gql[mt] = 0.f; }
    __hip_bfloat16* yb = ybf + (size_t)b * CDIM * N_POS;
    int nbase = n0 + w * 32;
    #pragma unroll
    for (int mt = 0; mt < 4; ++mt) {
        float4 bo = *reinterpret_cast<const float4*>(bout + mt * 16 + quad * 4);
        const float* bop = reinterpret_cast<const float*>(&bo);
        #pragma unroll
        for (int nt = 0; nt < 2; ++nt) {
            int n = nbase + nt * 16 + l15;
            #pragma unroll
            for (int r = 0; r < 4; ++r) {
                int o = mt * 16 + quad * 4 + r;
                float val = acc[mt][nt][r] + bop[r];
                yb[(size_t)o * N_POS + n] = __float2bfloat16(val);
                gsl[mt] += val; gql[mt] += val * val;
            }
        }
    }
    #pragma unroll
    for (int off = 16; off >= 1; off >>= 1) {
        #pragma unroll
        for (int mt = 0; mt < 4; ++mt) {
            gsl[mt] += __shfl_xor(gsl[mt], off, 64);
            gql[mt] += __shfl_xor(gql[mt], off, 64);
        }
    }
    if (l == 0 || l == 32) {
        int qh = quad >> 1;
        #pragma unroll
        for (int mt = 0; mt < 4; ++mt) {
            atomicAdd(&gsum[2 * mt + qh], gsl[mt]);
            atomicAdd(&gsq[2 * mt + qh], gql[mt]);
        }
    }
    __syncthreads();
    if (t < 8) {
        atomicAdd(&stats[(b * 8 + t) * 2],     gsum[t]);
        atomicAdd(&stats[(b * 8 + t) * 2 + 1], gsq[t]);
    }
}

// GN normalize: read bf16 pre-norm y, write fp32 out. Grid (9, 512).
__global__ __launch_bounds__(256) void gn_kernel(const __hip_bfloat16* __restrict__ ybf,
        float* __restrict__ out, const float* __restrict__ stats,
        const float* __restrict__ gamma, const float* __restrict__ beta) {
    int bc = blockIdx.y;            // 512 = b*64 + c
    int c = bc & 63, b = bc >> 6;
    int g = c >> 3;
    float s = stats[(b * 8 + g) * 2], q = stats[(b * 8 + g) * 2 + 1];
    const float invN = 1.f / (8.f * N_POS);
    float mean = s * invN;
    float var = q * invN - mean * mean;
    float sc = rsqrtf(var + EPS);
    float ga = gamma[c] * sc;
    float be = beta[c] - mean * sc * gamma[c];
    size_t base = ((size_t)b * CDIM + c) * N_POS + (size_t)(blockIdx.x * 256 + threadIdx.x) * 4;
    uint2 u = *reinterpret_cast<const uint2*>(ybf + base);
    float4 v;
    v.x = bf2f((short)(u.x & 0xffff)); v.y = bf2f((short)(u.x >> 16));
    v.z = bf2f((short)(u.y & 0xffff)); v.w = bf2f((short)(u.y >> 16));
    v.x = v.x * ga + be; v.y = v.y * ga + be; v.z = v.z * ga + be; v.w = v.w * ga + be;
    *reinterpret_cast<float4*>(out + base) = v;
}

extern "C" void kernel_launch(void* const* d_in, const int* in_sizes, int n_in,
                              void* d_out, int out_size, void* d_ws, size_t ws_size,
                              hipStream_t stream) {
    const float* x     = (const float*)d_in[0];
    const float* Wqkv  = (const float*)d_in[1];
    const float* Wout  = (const float*)d_in[2];
    const float* bout  = (const float*)d_in[3];
    const float* gamma = (const float*)d_in[4];
    const float* beta  = (const float*)d_in[5];
    float* out = (float*)d_out;

    float* stats  = (float*)d_ws;
    float* Pparts = stats + 128;
    float* Mp     = Pparts + PPARTS_TOT;
    __hip_bfloat16* wbf = (__hip_bfloat16*)(Mp + 4 * MP_SLICE);
    __hip_bfloat16* ybf = (__hip_bfloat16*)((char*)wbf + WBF_BYTES);

    wprep_kernel<<<dim3(24), 256, 0, stream>>>(Wqkv, wbf, stats);
    qkp_kernel<<<dim3(144, BATCH), 256, 0, stream>>>(x, wbf, Pparts);
    umat_kernel<<<dim3(NCHUNK, BATCH, HEADS), 256, 0, stream>>>(Wout, Wqkv, Pparts, Mp);
    y_kernel<<<dim3(72, BATCH), 256, 0, stream>>>(x, Mp, bout, ybf, stats);
    gn_kernel<<<dim3(9, 512), 256, 0, stream>>>(ybf, out, stats, gamma, beta);
}

// Round 3
// 132.720 us; speedup vs baseline: 1.1644x; 1.1644x over previous
//
#include <hip/hip_runtime.h>
#include <hip/hip_bf16.h>

#define N_POS 9216
#define NCHUNK 9
#define BATCH 8
#define CDIM 64
#define HEADS 4
#define EPS 1e-5f

// ws layout: stats fp32(128) | Pparts fp32 (72 chunks x 16 partials x 4096) |
//            Mp fp32 4x(72*4096) | Wbf16 | ybf bf16
#define NPART 16
#define PPARTS_TOT ((size_t)BATCH * NCHUNK * NPART * 4096)
#define MP_SLICE ((size_t)(BATCH * NCHUNK) * 4096)   // floats per head-partial of M
#define WBF_BYTES ((size_t)384 * 64 * 2)

typedef __attribute__((ext_vector_type(8))) short short8;
typedef __attribute__((ext_vector_type(4))) float f32x4;

static __device__ inline unsigned pk2(float a, float b) {
    __hip_bfloat162 h2(__float2bfloat16(a), __float2bfloat16(b));
    return *reinterpret_cast<unsigned*>(&h2);
}
static __device__ inline float bf2f(short s) {
    union { unsigned u; float f; } c; c.u = ((unsigned)(unsigned short)s) << 16; return c.f;
}

// Wqkv fp32 [384][64] -> bf16 [384][64]; also zeroes GN stats.
__global__ __launch_bounds__(256) void wprep_kernel(const float* __restrict__ Wqkv,
        __hip_bfloat16* __restrict__ wbf, float* __restrict__ stats) {
    int i = blockIdx.x * 256 + threadIdx.x;   // over 6144 float4
    if (i < 6144) {
        float4 v = ((const float4*)Wqkv)[i];
        uint2 u; u.x = pk2(v.x, v.y); u.y = pk2(v.z, v.w);
        ((uint2*)wbf)[i] = u;
    }
    if (i < 128) stats[i] = 0.f;
}

// qkp v3: grid (144, 8), 64 positions per block. Coalesced LDS staging of x
// (position-major lanes, 256B transactions) + in-register shfl k-softmax.
// Per block: stage -> sync -> qk MFMA (A=positions from LDS, B=wbf channels;
// wave w owns 64 channels) -> q: exp fused into transposed skT write;
// k: channel-softmax via shfl_xor over l15 lanes, transposed write -> sync ->
// per-head P(32x32) MFMA (K=64 positions) -> partial write.
// Only TWO barriers; xs/skT disjoint so no alias hazards.
// q normalization deferred (rowsum identity, handled in umat).
__global__ __launch_bounds__(256) void qkp_kernel(const float* __restrict__ x,
        const __hip_bfloat16* __restrict__ wbf, float* __restrict__ Pparts) {
    int bx = blockIdx.x;            // 144 = 9 ck x 16 pt
    int b  = blockIdx.y;
    int ck = bx >> 4, pt = bx & 15;
    __shared__ __align__(16) __hip_bfloat16 xs[64][72];     // 9.2 KB
    __shared__ __align__(16) __hip_bfloat16 skT[256][72];   // 36.9 KB
    int t = threadIdx.x, w = t >> 6, l = t & 63;
    int l15 = l & 15, quad = l >> 4;
    int n0 = bx * 64;

    // ---- stage x tile: lane = position (coalesced 256B loads)
    {
        int p = t & 63, cbase = (t >> 6) * 16;
        const float* xb = x + (size_t)b * CDIM * N_POS + n0 + p;
        #pragma unroll
        for (int j = 0; j < 16; j += 4) {
            float v0 = xb[(size_t)(cbase + j + 0) * N_POS];
            float v1 = xb[(size_t)(cbase + j + 1) * N_POS];
            float v2 = xb[(size_t)(cbase + j + 2) * N_POS];
            float v3 = xb[(size_t)(cbase + j + 3) * N_POS];
            uint2 u; u.x = pk2(v0, v1); u.y = pk2(v2, v3);
            *reinterpret_cast<uint2*>(&xs[p][cbase + j]) = u;
        }
    }
    __syncthreads();

    // ---- qk MFMA: D[pos 64][ch 64 of wave]; acc[mt][nt], col=l15=ch, row=quad*4+r=pos
    f32x4 acc[4][4];
    #pragma unroll
    for (int mt = 0; mt < 4; ++mt)
        #pragma unroll
        for (int nt = 0; nt < 4; ++nt) acc[mt][nt] = (f32x4){0.f, 0.f, 0.f, 0.f};
    #pragma unroll
    for (int ks = 0; ks < 2; ++ks) {
        int k0 = ks * 32 + quad * 8;
        short8 av[4];
        #pragma unroll
        for (int mt = 0; mt < 4; ++mt)
            av[mt] = *reinterpret_cast<const short8*>(&xs[mt * 16 + l15][k0]);
        #pragma unroll
        for (int nt = 0; nt < 4; ++nt) {
            short8 bw = *reinterpret_cast<const short8*>(wbf + (size_t)(w * 64 + nt * 16 + l15) * 64 + k0);
            #pragma unroll
            for (int mt = 0; mt < 4; ++mt)
                acc[mt][nt] = __builtin_amdgcn_mfma_f32_16x16x32_bf16(av[mt], bw, acc[mt][nt], 0, 0, 0);
        }
    }

    // ---- q (waves 0,1): exp fused into transposed write
    if (w < 2) {
        #pragma unroll
        for (int nt = 0; nt < 4; ++nt) {
            int ch = w * 64 + nt * 16 + l15;
            #pragma unroll
            for (int mt = 0; mt < 4; ++mt) {
                uint2 u;
                u.x = pk2(__expf(acc[mt][nt][0]), __expf(acc[mt][nt][1]));
                u.y = pk2(__expf(acc[mt][nt][2]), __expf(acc[mt][nt][3]));
                *reinterpret_cast<uint2*>(&skT[ch][mt * 16 + quad * 4]) = u;
            }
        }
    } else {
        // ---- k (waves 2,3): in-register channel softmax over 32 ch = 2 nt x 16 l15
        #pragma unroll
        for (int hh = 0; hh < 2; ++hh) {
            int h = (w - 2) * 2 + hh;
            #pragma unroll
            for (int mt = 0; mt < 4; ++mt) {
                f32x4 a0 = acc[mt][2 * hh], a1 = acc[mt][2 * hh + 1];
                f32x4 e0, e1;
                #pragma unroll
                for (int r = 0; r < 4; ++r) {
                    float m = fmaxf(a0[r], a1[r]);
                    m = fmaxf(m, __shfl_xor(m, 1));
                    m = fmaxf(m, __shfl_xor(m, 2));
                    m = fmaxf(m, __shfl_xor(m, 4));
                    m = fmaxf(m, __shfl_xor(m, 8));
                    float x0 = __expf(a0[r] - m), x1 = __expf(a1[r] - m);
                    float s = x0 + x1;
                    s += __shfl_xor(s, 1);
                    s += __shfl_xor(s, 2);
                    s += __shfl_xor(s, 4);
                    s += __shfl_xor(s, 8);
                    float is = 1.f / s;
                    e0[r] = x0 * is; e1[r] = x1 * is;
                }
                uint2 u;
                u.x = pk2(e0[0], e0[1]); u.y = pk2(e0[2], e0[3]);
                *reinterpret_cast<uint2*>(&skT[128 + h * 32 + l15][mt * 16 + quad * 4]) = u;
                u.x = pk2(e1[0], e1[1]); u.y = pk2(e1[2], e1[3]);
                *reinterpret_cast<uint2*>(&skT[128 + h * 32 + 16 + l15][mt * 16 + quad * 4]) = u;
            }
        }
    }
    __syncthreads();

    // ---- P MFMA: wave w = head w; P[d 32][dd 32], K = 64 block positions
    f32x4 pac[2][2];
    pac[0][0] = (f32x4){0,0,0,0}; pac[0][1] = (f32x4){0,0,0,0};
    pac[1][0] = (f32x4){0,0,0,0}; pac[1][1] = (f32x4){0,0,0,0};
    #pragma unroll
    for (int ks = 0; ks < 2; ++ks) {
        int k0 = ks * 32 + quad * 8;
        short8 aq0 = *reinterpret_cast<const short8*>(&skT[w * 32 + l15][k0]);
        short8 aq1 = *reinterpret_cast<const short8*>(&skT[w * 32 + 16 + l15][k0]);
        short8 bk0 = *reinterpret_cast<const short8*>(&skT[128 + w * 32 + l15][k0]);
        short8 bk1 = *reinterpret_cast<const short8*>(&skT[128 + w * 32 + 16 + l15][k0]);
        pac[0][0] = __builtin_amdgcn_mfma_f32_16x16x32_bf16(aq0, bk0, pac[0][0], 0, 0, 0);
        pac[0][1] = __builtin_amdgcn_mfma_f32_16x16x32_bf16(aq0, bk1, pac[0][1], 0, 0, 0);
        pac[1][0] = __builtin_amdgcn_mfma_f32_16x16x32_bf16(aq1, bk0, pac[1][0], 0, 0, 0);
        pac[1][1] = __builtin_amdgcn_mfma_f32_16x16x32_bf16(aq1, bk1, pac[1][1], 0, 0, 0);
    }
    float* Pp = Pparts + (((size_t)(b * NCHUNK + ck) * NPART + pt) * 4 + w) * 1024;
    #pragma unroll
    for (int tA = 0; tA < 2; ++tA)
        #pragma unroll
        for (int tB = 0; tB < 2; ++tB)
            #pragma unroll
            for (int r = 0; r < 4; ++r)
                Pp[(tA * 16 + quad * 4 + r) * 32 + tB * 16 + l15] = pac[tA][tB][r];
}

// Per (ck, b, h): sum 16 partials -> P; iZ = 1/rowsum; U'_h = Wout_h.diag(iZ).P;
// M-partial_h = U'_h . Wv_h (64x64 fp32). y-kernel sums the 4 head-partials.
__global__ __launch_bounds__(256) void umat_kernel(const float* __restrict__ Wout,
        const float* __restrict__ Wqkv, const float* __restrict__ Pparts,
        float* __restrict__ Mp) {
    int ck = blockIdx.x, b = blockIdx.y, h = blockIdx.z;
    int t = threadIdx.x;
    __shared__ float Pl[32][32];
    __shared__ float iZ[32];
    __shared__ float Ul[64][33];    // U'_h, +1 pad
    __shared__ float Wvh[32][68];   // Wv rows of this head, fp32, padded
    {
        const float4* P0 = (const float4*)Pparts
            + ((size_t)(b * NCHUNK + ck) * NPART) * 1024 + h * 256 + t;
        float4 s = (float4){0.f, 0.f, 0.f, 0.f};
        #pragma unroll
        for (int pt = 0; pt < NPART; ++pt) {
            float4 a = P0[pt * 1024];
            s.x += a.x; s.y += a.y; s.z += a.z; s.w += a.w;
        }
        ((float4*)Pl)[t] = s;
    }
    {   // stage Wv_h
        int e = t >> 3, cq = t & 7;
        const float4* wr = (const float4*)(Wqkv + (size_t)(256 + h * 32 + e) * 64 + cq * 8);
        float4 a0 = wr[0], a1 = wr[1];
        *reinterpret_cast<float4*>(&Wvh[e][cq * 8])     = a0;
        *reinterpret_cast<float4*>(&Wvh[e][cq * 8 + 4]) = a1;
    }
    __syncthreads();
    if (t < 32) {
        float s = 0.f;
        #pragma unroll
        for (int c = 0; c < 32; ++c) s += Pl[t][c];
        iZ[t] = 1.f / s;
    }
    __syncthreads();
    int o = t & 63, wv = t >> 6;
    float wz[32];
    {
        const float4* wr = (const float4*)(Wout + (size_t)o * 128 + h * 32);
        #pragma unroll
        for (int j = 0; j < 8; ++j) {
            float4 f = wr[j];
            wz[j*4+0] = f.x * iZ[j*4+0]; wz[j*4+1] = f.y * iZ[j*4+1];
            wz[j*4+2] = f.z * iZ[j*4+2]; wz[j*4+3] = f.w * iZ[j*4+3];
        }
    }
    float ua[8];
    #pragma unroll
    for (int j = 0; j < 8; ++j) ua[j] = 0.f;
    for (int d = 0; d < 32; ++d) {
        float wd = wz[d];
        #pragma unroll
        for (int j = 0; j < 8; ++j) ua[j] += wd * Pl[d][wv * 8 + j];
    }
    #pragma unroll
    for (int j = 0; j < 8; ++j) Ul[o][wv * 8 + j] = ua[j];
    __syncthreads();

    float macc[16];
    #pragma unroll
    for (int j = 0; j < 16; ++j) macc[j] = 0.f;
    for (int e = 0; e < 32; ++e) {
        float u = Ul[o][e];
        const float4* wvp = reinterpret_cast<const float4*>(&Wvh[e][wv * 16]);
        #pragma unroll
        for (int q = 0; q < 4; ++q) {
            float4 f = wvp[q];
            macc[q*4+0] += u * f.x; macc[q*4+1] += u * f.y;
            macc[q*4+2] += u * f.z; macc[q*4+3] += u * f.w;
        }
    }
    float* mp = Mp + (size_t)h * MP_SLICE + ((size_t)(b * NCHUNK + ck)) * 4096
              + (size_t)o * 64 + wv * 16;
    #pragma unroll
    for (int q = 0; q < 4; ++q) {
        float4 f; f.x = macc[q*4+0]; f.y = macc[q*4+1]; f.z = macc[q*4+2]; f.w = macc[q*4+3];
        reinterpret_cast<float4*>(mp)[q] = f;
    }
}

// y = M . x + bias, fused GN stats. Single K=64 GEMM per 128-position tile:
// A = M (bf16 in LDS, summed over 4 head-partials), B = x tile (bf16 in LDS).
// (R1 version — coalesced staging.)
__global__ __launch_bounds__(256) void y_kernel(const float* __restrict__ x,
        const float* __restrict__ Mp, const float* __restrict__ bout,
        __hip_bfloat16* __restrict__ ybf, float* __restrict__ stats) {
    int bx = blockIdx.x;   // 72 tiles of 128 positions
    int b  = blockIdx.y;   // 8
    int ck = bx >> 3;
    int n0 = bx * 128;
    __shared__ __align__(16) __hip_bfloat16 xs[128][72];   // 18.4 KB
    __shared__ __align__(16) __hip_bfloat16 Ml[64][72];    // 9.2 KB
    __shared__ float gsum[8], gsq[8];
    int t = threadIdx.x, w = t >> 6, l = t & 63;
    int l15 = l & 15, quad = l >> 4;
    if (t < 8) { gsum[t] = 0.f; gsq[t] = 0.f; }

    // stage x tile: 2 threads per position, 32 channels each
    {
        int p = t & 127, cbase = (t >> 7) * 32;
        const float* xb = x + (size_t)b * CDIM * N_POS + n0 + p;
        #pragma unroll
        for (int j = 0; j < 32; j += 4) {
            float v0 = xb[(size_t)(cbase + j + 0) * N_POS];
            float v1 = xb[(size_t)(cbase + j + 1) * N_POS];
            float v2 = xb[(size_t)(cbase + j + 2) * N_POS];
            float v3 = xb[(size_t)(cbase + j + 3) * N_POS];
            uint2 u; u.x = pk2(v0, v1); u.y = pk2(v2, v3);
            *reinterpret_cast<uint2*>(&xs[p][cbase + j]) = u;
        }
    }
    // stage M: sum 4 head-partials (L2-hot), cvt to bf16
    {
        int o = t >> 2, cs = (t & 3) * 16;
        const float* mb = Mp + ((size_t)(b * NCHUNK + ck)) * 4096 + (size_t)o * 64 + cs;
        float m[16];
        #pragma unroll
        for (int q = 0; q < 4; ++q) {
            float4 f = reinterpret_cast<const float4*>(mb)[q];
            m[q*4+0] = f.x; m[q*4+1] = f.y; m[q*4+2] = f.z; m[q*4+3] = f.w;
        }
        #pragma unroll
        for (int h = 1; h < 4; ++h) {
            const float* mh = mb + h * MP_SLICE;
            #pragma unroll
            for (int q = 0; q < 4; ++q) {
                float4 f = reinterpret_cast<const float4*>(mh)[q];
                m[q*4+0] += f.x; m[q*4+1] += f.y; m[q*4+2] += f.z; m[q*4+3] += f.w;
            }
        }
        #pragma unroll
        for (int q = 0; q < 4; ++q) {
            uint2 u; u.x = pk2(m[q*4+0], m[q*4+1]); u.y = pk2(m[q*4+2], m[q*4+3]);
            *reinterpret_cast<uint2*>(&Ml[o][cs + q * 4]) = u;
        }
    }
    __syncthreads();

    // y MFMA: A = M rows (out-ch), B = x position rows, K = 64 channels
    int nw = w * 32;
    f32x4 acc[4][2];
    #pragma unroll
    for (int mt = 0; mt < 4; ++mt) { acc[mt][0] = (f32x4){0,0,0,0}; acc[mt][1] = (f32x4){0,0,0,0}; }
    #pragma unroll
    for (int ks = 0; ks < 2; ++ks) {
        int k0 = ks * 32 + quad * 8;
        short8 bf[2];
        #pragma unroll
        for (int nt = 0; nt < 2; ++nt)
            bf[nt] = *reinterpret_cast<const short8*>(&xs[nw + nt * 16 + l15][k0]);
        #pragma unroll
        for (int mt = 0; mt < 4; ++mt) {
            short8 af = *reinterpret_cast<const short8*>(&Ml[mt * 16 + l15][k0]);
            acc[mt][0] = __builtin_amdgcn_mfma_f32_16x16x32_bf16(af, bf[0], acc[mt][0], 0, 0, 0);
            acc[mt][1] = __builtin_amdgcn_mfma_f32_16x16x32_bf16(af, bf[1], acc[mt][1], 0, 0, 0);
        }
    }
    float gsl[4], gql[4];
    #pragma unroll
    for (int mt = 0; mt < 4; ++mt) { gsl[mt] = 0.f; gql[mt] = 0.f; }
    __hip_bfloat16* yb = ybf + (size_t)b * CDIM * N_POS;
    int nbase = n0 + nw;
    #pragma unroll
    for (int mt = 0; mt < 4; ++mt) {
        float4 bo = *reinterpret_cast<const float4*>(bout + mt * 16 + quad * 4);
        const float* bop = reinterpret_cast<const float*>(&bo);
        #pragma unroll
        for (int nt = 0; nt < 2; ++nt) {
            int n = nbase + nt * 16 + l15;
            #pragma unroll
            for (int r = 0; r < 4; ++r) {
                int o = mt * 16 + quad * 4 + r;
                float val = acc[mt][nt][r] + bop[r];
                yb[(size_t)o * N_POS + n] = __float2bfloat16(val);
                gsl[mt] += val; gql[mt] += val * val;
            }
        }
    }
    #pragma unroll
    for (int off = 16; off >= 1; off >>= 1) {
        #pragma unroll
        for (int mt = 0; mt < 4; ++mt) {
            gsl[mt] += __shfl_xor(gsl[mt], off, 64);
            gql[mt] += __shfl_xor(gql[mt], off, 64);
        }
    }
    if (l == 0 || l == 32) {
        int qh = quad >> 1;
        #pragma unroll
        for (int mt = 0; mt < 4; ++mt) {
            atomicAdd(&gsum[2 * mt + qh], gsl[mt]);
            atomicAdd(&gsq[2 * mt + qh], gql[mt]);
        }
    }
    __syncthreads();
    if (t < 8) {
        atomicAdd(&stats[(b * 8 + t) * 2],     gsum[t]);
        atomicAdd(&stats[(b * 8 + t) * 2 + 1], gsq[t]);
    }
}

// GN normalize: read bf16 pre-norm y, write fp32 out. Grid (9, 512).
__global__ __launch_bounds__(256) void gn_kernel(const __hip_bfloat16* __restrict__ ybf,
        float* __restrict__ out, const float* __restrict__ stats,
        const float* __restrict__ gamma, const float* __restrict__ beta) {
    int bc = blockIdx.y;            // 512 = b*64 + c
    int c = bc & 63, b = bc >> 6;
    int g = c >> 3;
    float s = stats[(b * 8 + g) * 2], q = stats[(b * 8 + g) * 2 + 1];
    const float invN = 1.f / (8.f * N_POS);
    float mean = s * invN;
    float var = q * invN - mean * mean;
    float sc = rsqrtf(var + EPS);
    float ga = gamma[c] * sc;
    float be = beta[c] - mean * sc * gamma[c];
    size_t base = ((size_t)b * CDIM + c) * N_POS + (size_t)(blockIdx.x * 256 + threadIdx.x) * 4;
    uint2 u = *reinterpret_cast<const uint2*>(ybf + base);
    float4 v;
    v.x = bf2f((short)(u.x & 0xffff)); v.y = bf2f((short)(u.x >> 16));
    v.z = bf2f((short)(u.y & 0xffff)); v.w = bf2f((short)(u.y >> 16));
    v.x = v.x * ga + be; v.y = v.y * ga + be; v.z = v.z * ga + be; v.w = v.w * ga + be;
    *reinterpret_cast<float4*>(out + base) = v;
}

extern "C" void kernel_launch(void* const* d_in, const int* in_sizes, int n_in,
                              void* d_out, int out_size, void* d_ws, size_t ws_size,
                              hipStream_t stream) {
    const float* x     = (const float*)d_in[0];
    const float* Wqkv  = (const float*)d_in[1];
    const float* Wout  = (const float*)d_in[2];
    const float* bout  = (const float*)d_in[3];
    const float* gamma = (const float*)d_in[4];
    const float* beta  = (const float*)d_in[5];
    float* out = (float*)d_out;

    float* stats  = (float*)d_ws;
    float* Pparts = stats + 128;
    float* Mp     = Pparts + PPARTS_TOT;
    __hip_bfloat16* wbf = (__hip_bfloat16*)(Mp + 4 * MP_SLICE);
    __hip_bfloat16* ybf = (__hip_bfloat16*)((char*)wbf + WBF_BYTES);

    wprep_kernel<<<dim3(24), 256, 0, stream>>>(Wqkv, wbf, stats);
    qkp_kernel<<<dim3(144, BATCH), 256, 0, stream>>>(x, wbf, Pparts);
    umat_kernel<<<dim3(NCHUNK, BATCH, HEADS), 256, 0, stream>>>(Wout, Wqkv, Pparts, Mp);
    y_kernel<<<dim3(72, BATCH), 256, 0, stream>>>(x, Mp, bout, ybf, stats);
    gn_kernel<<<dim3(9, 512), 256, 0, stream>>>(ybf, out, stats, gamma, beta);
}

// Round 4
// 130.855 us; speedup vs baseline: 1.1810x; 1.0143x over previous
//
#include <hip/hip_runtime.h>
#include <hip/hip_bf16.h>

#define N_POS 9216
#define NCHUNK 9
#define BATCH 8
#define CDIM 64
#define HEADS 4
#define EPS 1e-5f

// ws layout: stats fp32(128) | Pparts fp32 (72 chunks x 16 partials x 4096) |
//            Mp fp32 4x(72*4096) | Wbf16 | ybf bf16
#define NPART 16
#define PPARTS_TOT ((size_t)BATCH * NCHUNK * NPART * 4096)
#define MP_SLICE ((size_t)(BATCH * NCHUNK) * 4096)   // floats per head-partial of M
#define WBF_BYTES ((size_t)384 * 64 * 2)

typedef __attribute__((ext_vector_type(8))) short short8;
typedef __attribute__((ext_vector_type(4))) float f32x4;

static __device__ inline unsigned pk2(float a, float b) {
    __hip_bfloat162 h2(__float2bfloat16(a), __float2bfloat16(b));
    return *reinterpret_cast<unsigned*>(&h2);
}
static __device__ inline float bf2f(short s) {
    union { unsigned u; float f; } c; c.u = ((unsigned)(unsigned short)s) << 16; return c.f;
}
static __device__ inline short8 mk8(unsigned a, unsigned b, unsigned c, unsigned d) {
    union { short8 s; unsigned u[4]; } cv;
    cv.u[0] = a; cv.u[1] = b; cv.u[2] = c; cv.u[3] = d; return cv.s;
}

// Wqkv fp32 [384][64] -> bf16 [384][64]; also zeroes GN stats.
__global__ __launch_bounds__(256) void wprep_kernel(const float* __restrict__ Wqkv,
        __hip_bfloat16* __restrict__ wbf, float* __restrict__ stats) {
    int i = blockIdx.x * 256 + threadIdx.x;   // over 6144 float4
    if (i < 6144) {
        float4 v = ((const float4*)Wqkv)[i];
        uint2 u; u.x = pk2(v.x, v.y); u.y = pk2(v.z, v.w);
        ((uint2*)wbf)[i] = u;
    }
    if (i < 128) stats[i] = 0.f;
}

// qkp v4: grid (144, 8), 64 positions/block, wave = head. ONE barrier, 9.2 KB LDS.
// Stage x coalesced -> sync -> qk MFMA (nt 0,1 = head's q-ch, nt 2,3 = head's
// k-ch; D has col=l15=channel, row=quad*4+r=position) -> in-register k-softmax
// (shfl_xor over l15) + q-exp -> pack bf16 -> SHUFFLE-transpose (quad-group
// permutation; D's 4-pos-per-lane over 4 mt tiles -> P-frag's 8-consecutive-pos
// per lane) -> per-head P(32x32) MFMA -> partial write. No skT, no 2nd barrier.
// q normalization deferred (rowsum identity, handled in umat).
__global__ __launch_bounds__(256) void qkp_kernel(const float* __restrict__ x,
        const __hip_bfloat16* __restrict__ wbf, float* __restrict__ Pparts) {
    int bx = blockIdx.x;            // 144 = 9 ck x 16 pt
    int b  = blockIdx.y;
    int ck = bx >> 4, pt = bx & 15;
    __shared__ __align__(16) __hip_bfloat16 xs[64][72];     // 9.2 KB only
    int t = threadIdx.x, w = t >> 6, l = t & 63;
    int l15 = l & 15, quad = l >> 4;
    int n0 = bx * 64;

    // ---- stage x tile: lane = position (coalesced 256B loads)
    {
        int p = t & 63, cbase = (t >> 6) * 16;
        const float* xb = x + (size_t)b * CDIM * N_POS + n0 + p;
        #pragma unroll
        for (int j = 0; j < 16; j += 4) {
            float v0 = xb[(size_t)(cbase + j + 0) * N_POS];
            float v1 = xb[(size_t)(cbase + j + 1) * N_POS];
            float v2 = xb[(size_t)(cbase + j + 2) * N_POS];
            float v3 = xb[(size_t)(cbase + j + 3) * N_POS];
            uint2 u; u.x = pk2(v0, v1); u.y = pk2(v2, v3);
            *reinterpret_cast<uint2*>(&xs[p][cbase + j]) = u;
        }
    }
    __syncthreads();   // the ONLY barrier

    // ---- qk MFMA: acc[mt][nt]; nt 0,1 = q-ch of head w, nt 2,3 = k-ch of head w
    f32x4 acc[4][4];
    #pragma unroll
    for (int mt = 0; mt < 4; ++mt)
        #pragma unroll
        for (int nt = 0; nt < 4; ++nt) acc[mt][nt] = (f32x4){0.f, 0.f, 0.f, 0.f};
    #pragma unroll
    for (int ks = 0; ks < 2; ++ks) {
        int k0 = ks * 32 + quad * 8;
        short8 av[4];
        #pragma unroll
        for (int mt = 0; mt < 4; ++mt)
            av[mt] = *reinterpret_cast<const short8*>(&xs[mt * 16 + l15][k0]);
        #pragma unroll
        for (int nt = 0; nt < 4; ++nt) {
            int row = (nt < 2) ? (w * 32 + nt * 16 + l15)
                               : (128 + w * 32 + (nt - 2) * 16 + l15);
            short8 bw = *reinterpret_cast<const short8*>(wbf + (size_t)row * 64 + k0);
            #pragma unroll
            for (int mt = 0; mt < 4; ++mt)
                acc[mt][nt] = __builtin_amdgcn_mfma_f32_16x16x32_bf16(av[mt], bw, acc[mt][nt], 0, 0, 0);
        }
    }

    // ---- softmax/exp in-register, pack to bf16 pairs: pk[mt][nt][pair]
    unsigned pk[4][4][2];
    #pragma unroll
    for (int mt = 0; mt < 4; ++mt) {
        f32x4 e2, e3;
        #pragma unroll
        for (int r = 0; r < 4; ++r) {
            float a2 = acc[mt][2][r], a3 = acc[mt][3][r];
            float m = fmaxf(a2, a3);
            m = fmaxf(m, __shfl_xor(m, 1));
            m = fmaxf(m, __shfl_xor(m, 2));
            m = fmaxf(m, __shfl_xor(m, 4));
            m = fmaxf(m, __shfl_xor(m, 8));
            float x2 = __expf(a2 - m), x3 = __expf(a3 - m);
            float s = x2 + x3;
            s += __shfl_xor(s, 1);
            s += __shfl_xor(s, 2);
            s += __shfl_xor(s, 4);
            s += __shfl_xor(s, 8);
            float is = 1.f / s;
            e2[r] = x2 * is; e3[r] = x3 * is;
        }
        pk[mt][2][0] = pk2(e2[0], e2[1]); pk[mt][2][1] = pk2(e2[2], e2[3]);
        pk[mt][3][0] = pk2(e3[0], e3[1]); pk[mt][3][1] = pk2(e3[2], e3[3]);
        pk[mt][0][0] = pk2(__expf(acc[mt][0][0]), __expf(acc[mt][0][1]));
        pk[mt][0][1] = pk2(__expf(acc[mt][0][2]), __expf(acc[mt][0][3]));
        pk[mt][1][0] = pk2(__expf(acc[mt][1][0]), __expf(acc[mt][1][1]));
        pk[mt][1][1] = pk2(__expf(acc[mt][1][2]), __expf(acc[mt][1][3]));
    }

    // ---- shuffle-transpose to P-fragments + P MFMA
    // A/B-frag (tile, ks), lane (l15,quad), slot s: k-pos p = ks*32+quad*8+2s..
    //   source lane = ((quad&1)*2 + (s>>1))*16 + l15
    //   source reg  = pk[2ks + (quad>>1)][nt][s&1]
    f32x4 pac[2][2];
    pac[0][0] = (f32x4){0,0,0,0}; pac[0][1] = (f32x4){0,0,0,0};
    pac[1][0] = (f32x4){0,0,0,0}; pac[1][1] = (f32x4){0,0,0,0};
    int srcbase = ((quad & 1) * 2) * 16 + l15;
    bool hiHalf = (quad >= 2);
    #pragma unroll
    for (int ks = 0; ks < 2; ++ks) {
        unsigned fr[4][4];
        #pragma unroll
        for (int nt = 0; nt < 4; ++nt) {
            #pragma unroll
            for (int s = 0; s < 4; ++s) {
                int src = srcbase + (s >> 1) * 16;
                unsigned lo = __shfl(pk[2 * ks][nt][s & 1], src);
                unsigned hi = __shfl(pk[2 * ks + 1][nt][s & 1], src);
                fr[nt][s] = hiHalf ? hi : lo;
            }
        }
        short8 A0 = mk8(fr[0][0], fr[0][1], fr[0][2], fr[0][3]);
        short8 A1 = mk8(fr[1][0], fr[1][1], fr[1][2], fr[1][3]);
        short8 B0 = mk8(fr[2][0], fr[2][1], fr[2][2], fr[2][3]);
        short8 B1 = mk8(fr[3][0], fr[3][1], fr[3][2], fr[3][3]);
        pac[0][0] = __builtin_amdgcn_mfma_f32_16x16x32_bf16(A0, B0, pac[0][0], 0, 0, 0);
        pac[0][1] = __builtin_amdgcn_mfma_f32_16x16x32_bf16(A0, B1, pac[0][1], 0, 0, 0);
        pac[1][0] = __builtin_amdgcn_mfma_f32_16x16x32_bf16(A1, B0, pac[1][0], 0, 0, 0);
        pac[1][1] = __builtin_amdgcn_mfma_f32_16x16x32_bf16(A1, B1, pac[1][1], 0, 0, 0);
    }
    float* Pp = Pparts + (((size_t)(b * NCHUNK + ck) * NPART + pt) * 4 + w) * 1024;
    #pragma unroll
    for (int tA = 0; tA < 2; ++tA)
        #pragma unroll
        for (int tB = 0; tB < 2; ++tB)
            #pragma unroll
            for (int r = 0; r < 4; ++r)
                Pp[(tA * 16 + quad * 4 + r) * 32 + tB * 16 + l15] = pac[tA][tB][r];
}

// Per (ck, b, h): sum 16 partials -> P; iZ = 1/rowsum; U'_h = Wout_h.diag(iZ).P;
// M-partial_h = U'_h . Wv_h (64x64 fp32). y-kernel sums the 4 head-partials.
__global__ __launch_bounds__(256) void umat_kernel(const float* __restrict__ Wout,
        const float* __restrict__ Wqkv, const float* __restrict__ Pparts,
        float* __restrict__ Mp) {
    int ck = blockIdx.x, b = blockIdx.y, h = blockIdx.z;
    int t = threadIdx.x;
    __shared__ float Pl[32][32];
    __shared__ float iZ[32];
    __shared__ float Ul[64][33];    // U'_h, +1 pad
    __shared__ float Wvh[32][68];   // Wv rows of this head, fp32, padded
    {
        const float4* P0 = (const float4*)Pparts
            + ((size_t)(b * NCHUNK + ck) * NPART) * 1024 + h * 256 + t;
        float4 s = (float4){0.f, 0.f, 0.f, 0.f};
        #pragma unroll
        for (int pt = 0; pt < NPART; ++pt) {
            float4 a = P0[pt * 1024];
            s.x += a.x; s.y += a.y; s.z += a.z; s.w += a.w;
        }
        ((float4*)Pl)[t] = s;
    }
    {   // stage Wv_h
        int e = t >> 3, cq = t & 7;
        const float4* wr = (const float4*)(Wqkv + (size_t)(256 + h * 32 + e) * 64 + cq * 8);
        float4 a0 = wr[0], a1 = wr[1];
        *reinterpret_cast<float4*>(&Wvh[e][cq * 8])     = a0;
        *reinterpret_cast<float4*>(&Wvh[e][cq * 8 + 4]) = a1;
    }
    __syncthreads();
    if (t < 32) {
        float s = 0.f;
        #pragma unroll
        for (int c = 0; c < 32; ++c) s += Pl[t][c];
        iZ[t] = 1.f / s;
    }
    __syncthreads();
    int o = t & 63, wv = t >> 6;
    float wz[32];
    {
        const float4* wr = (const float4*)(Wout + (size_t)o * 128 + h * 32);
        #pragma unroll
        for (int j = 0; j < 8; ++j) {
            float4 f = wr[j];
            wz[j*4+0] = f.x * iZ[j*4+0]; wz[j*4+1] = f.y * iZ[j*4+1];
            wz[j*4+2] = f.z * iZ[j*4+2]; wz[j*4+3] = f.w * iZ[j*4+3];
        }
    }
    float ua[8];
    #pragma unroll
    for (int j = 0; j < 8; ++j) ua[j] = 0.f;
    for (int d = 0; d < 32; ++d) {
        float wd = wz[d];
        #pragma unroll
        for (int j = 0; j < 8; ++j) ua[j] += wd * Pl[d][wv * 8 + j];
    }
    #pragma unroll
    for (int j = 0; j < 8; ++j) Ul[o][wv * 8 + j] = ua[j];
    __syncthreads();

    float macc[16];
    #pragma unroll
    for (int j = 0; j < 16; ++j) macc[j] = 0.f;
    for (int e = 0; e < 32; ++e) {
        float u = Ul[o][e];
        const float4* wvp = reinterpret_cast<const float4*>(&Wvh[e][wv * 16]);
        #pragma unroll
        for (int q = 0; q < 4; ++q) {
            float4 f = wvp[q];
            macc[q*4+0] += u * f.x; macc[q*4+1] += u * f.y;
            macc[q*4+2] += u * f.z; macc[q*4+3] += u * f.w;
        }
    }
    float* mp = Mp + (size_t)h * MP_SLICE + ((size_t)(b * NCHUNK + ck)) * 4096
              + (size_t)o * 64 + wv * 16;
    #pragma unroll
    for (int q = 0; q < 4; ++q) {
        float4 f; f.x = macc[q*4+0]; f.y = macc[q*4+1]; f.z = macc[q*4+2]; f.w = macc[q*4+3];
        reinterpret_cast<float4*>(mp)[q] = f;
    }
}

// y = M . x + bias, fused GN stats. Single K=64 GEMM per 128-position tile:
// A = M (bf16 in LDS, summed over 4 head-partials), B = x tile (bf16 in LDS).
__global__ __launch_bounds__(256) void y_kernel(const float* __restrict__ x,
        const float* __restrict__ Mp, const float* __restrict__ bout,
        __hip_bfloat16* __restrict__ ybf, float* __restrict__ stats) {
    int bx = blockIdx.x;   // 72 tiles of 128 positions
    int b  = blockIdx.y;   // 8
    int ck = bx >> 3;
    int n0 = bx * 128;
    __shared__ __align__(16) __hip_bfloat16 xs[128][72];   // 18.4 KB
    __shared__ __align__(16) __hip_bfloat16 Ml[64][72];    // 9.2 KB
    __shared__ float gsum[8], gsq[8];
    int t = threadIdx.x, w = t >> 6, l = t & 63;
    int l15 = l & 15, quad = l >> 4;
    if (t < 8) { gsum[t] = 0.f; gsq[t] = 0.f; }

    // stage x tile: 2 threads per position, 32 channels each
    {
        int p = t & 127, cbase = (t >> 7) * 32;
        const float* xb = x + (size_t)b * CDIM * N_POS + n0 + p;
        #pragma unroll
        for (int j = 0; j < 32; j += 4) {
            float v0 = xb[(size_t)(cbase + j + 0) * N_POS];
            float v1 = xb[(size_t)(cbase + j + 1) * N_POS];
            float v2 = xb[(size_t)(cbase + j + 2) * N_POS];
            float v3 = xb[(size_t)(cbase + j + 3) * N_POS];
            uint2 u; u.x = pk2(v0, v1); u.y = pk2(v2, v3);
            *reinterpret_cast<uint2*>(&xs[p][cbase + j]) = u;
        }
    }
    // stage M: sum 4 head-partials (L2-hot), cvt to bf16
    {
        int o = t >> 2, cs = (t & 3) * 16;
        const float* mb = Mp + ((size_t)(b * NCHUNK + ck)) * 4096 + (size_t)o * 64 + cs;
        float m[16];
        #pragma unroll
        for (int q = 0; q < 4; ++q) {
            float4 f = reinterpret_cast<const float4*>(mb)[q];
            m[q*4+0] = f.x; m[q*4+1] = f.y; m[q*4+2] = f.z; m[q*4+3] = f.w;
        }
        #pragma unroll
        for (int h = 1; h < 4; ++h) {
            const float* mh = mb + h * MP_SLICE;
            #pragma unroll
            for (int q = 0; q < 4; ++q) {
                float4 f = reinterpret_cast<const float4*>(mh)[q];
                m[q*4+0] += f.x; m[q*4+1] += f.y; m[q*4+2] += f.z; m[q*4+3] += f.w;
            }
        }
        #pragma unroll
        for (int q = 0; q < 4; ++q) {
            uint2 u; u.x = pk2(m[q*4+0], m[q*4+1]); u.y = pk2(m[q*4+2], m[q*4+3]);
            *reinterpret_cast<uint2*>(&Ml[o][cs + q * 4]) = u;
        }
    }
    __syncthreads();

    // y MFMA: A = M rows (out-ch), B = x position rows, K = 64 channels
    int nw = w * 32;
    f32x4 acc[4][2];
    #pragma unroll
    for (int mt = 0; mt < 4; ++mt) { acc[mt][0] = (f32x4){0,0,0,0}; acc[mt][1] = (f32x4){0,0,0,0}; }
    #pragma unroll
    for (int ks = 0; ks < 2; ++ks) {
        int k0 = ks * 32 + quad * 8;
        short8 bf[2];
        #pragma unroll
        for (int nt = 0; nt < 2; ++nt)
            bf[nt] = *reinterpret_cast<const short8*>(&xs[nw + nt * 16 + l15][k0]);
        #pragma unroll
        for (int mt = 0; mt < 4; ++mt) {
            short8 af = *reinterpret_cast<const short8*>(&Ml[mt * 16 + l15][k0]);
            acc[mt][0] = __builtin_amdgcn_mfma_f32_16x16x32_bf16(af, bf[0], acc[mt][0], 0, 0, 0);
            acc[mt][1] = __builtin_amdgcn_mfma_f32_16x16x32_bf16(af, bf[1], acc[mt][1], 0, 0, 0);
        }
    }
    float gsl[4], gql[4];
    #pragma unroll
    for (int mt = 0; mt < 4; ++mt) { gsl[mt] = 0.f; gql[mt] = 0.f; }
    __hip_bfloat16* yb = ybf + (size_t)b * CDIM * N_POS;
    int nbase = n0 + nw;
    #pragma unroll
    for (int mt = 0; mt < 4; ++mt) {
        float4 bo = *reinterpret_cast<const float4*>(bout + mt * 16 + quad * 4);
        const float* bop = reinterpret_cast<const float*>(&bo);
        #pragma unroll
        for (int nt = 0; nt < 2; ++nt) {
            int n = nbase + nt * 16 + l15;
            #pragma unroll
            for (int r = 0; r < 4; ++r) {
                int o = mt * 16 + quad * 4 + r;
                float val = acc[mt][nt][r] + bop[r];
                yb[(size_t)o * N_POS + n] = __float2bfloat16(val);
                gsl[mt] += val; gql[mt] += val * val;
            }
        }
    }
    #pragma unroll
    for (int off = 16; off >= 1; off >>= 1) {
        #pragma unroll
        for (int mt = 0; mt < 4; ++mt) {
            gsl[mt] += __shfl_xor(gsl[mt], off, 64);
            gql[mt] += __shfl_xor(gql[mt], off, 64);
        }
    }
    if (l == 0 || l == 32) {
        int qh = quad >> 1;
        #pragma unroll
        for (int mt = 0; mt < 4; ++mt) {
            atomicAdd(&gsum[2 * mt + qh], gsl[mt]);
            atomicAdd(&gsq[2 * mt + qh], gql[mt]);
        }
    }
    __syncthreads();
    if (t < 8) {
        atomicAdd(&stats[(b * 8 + t) * 2],     gsum[t]);
        atomicAdd(&stats[(b * 8 + t) * 2 + 1], gsq[t]);
    }
}

// GN normalize: read bf16 pre-norm y, write fp32 out. Grid (9, 512).
__global__ __launch_bounds__(256) void gn_kernel(const __hip_bfloat16* __restrict__ ybf,
        float* __restrict__ out, const float* __restrict__ stats,
        const float* __restrict__ gamma, const float* __restrict__ beta) {
    int bc = blockIdx.y;            // 512 = b*64 + c
    int c = bc & 63, b = bc >> 6;
    int g = c >> 3;
    float s = stats[(b * 8 + g) * 2], q = stats[(b * 8 + g) * 2 + 1];
    const float invN = 1.f / (8.f * N_POS);
    float mean = s * invN;
    float var = q * invN - mean * mean;
    float sc = rsqrtf(var + EPS);
    float ga = gamma[c] * sc;
    float be = beta[c] - mean * sc * gamma[c];
    size_t base = ((size_t)b * CDIM + c) * N_POS + (size_t)(blockIdx.x * 256 + threadIdx.x) * 4;
    uint2 u = *reinterpret_cast<const uint2*>(ybf + base);
    float4 v;
    v.x = bf2f((short)(u.x & 0xffff)); v.y = bf2f((short)(u.x >> 16));
    v.z = bf2f((short)(u.y & 0xffff)); v.w = bf2f((short)(u.y >> 16));
    v.x = v.x * ga + be; v.y = v.y * ga + be; v.z = v.z * ga + be; v.w = v.w * ga + be;
    *reinterpret_cast<float4*>(out + base) = v;
}

extern "C" void kernel_launch(void* const* d_in, const int* in_sizes, int n_in,
                              void* d_out, int out_size, void* d_ws, size_t ws_size,
                              hipStream_t stream) {
    const float* x     = (const float*)d_in[0];
    const float* Wqkv  = (const float*)d_in[1];
    const float* Wout  = (const float*)d_in[2];
    const float* bout  = (const float*)d_in[3];
    const float* gamma = (const float*)d_in[4];
    const float* beta  = (const float*)d_in[5];
    float* out = (float*)d_out;

    float* stats  = (float*)d_ws;
    float* Pparts = stats + 128;
    float* Mp     = Pparts + PPARTS_TOT;
    __hip_bfloat16* wbf = (__hip_bfloat16*)(Mp + 4 * MP_SLICE);
    __hip_bfloat16* ybf = (__hip_bfloat16*)((char*)wbf + WBF_BYTES);

    wprep_kernel<<<dim3(24), 256, 0, stream>>>(Wqkv, wbf, stats);
    qkp_kernel<<<dim3(144, BATCH), 256, 0, stream>>>(x, wbf, Pparts);
    umat_kernel<<<dim3(NCHUNK, BATCH, HEADS), 256, 0, stream>>>(Wout, Wqkv, Pparts, Mp);
    y_kernel<<<dim3(72, BATCH), 256, 0, stream>>>(x, Mp, bout, ybf, stats);
    gn_kernel<<<dim3(9, 512), 256, 0, stream>>>(ybf, out, stats, gamma, beta);
}